// Round 2
// baseline (319.282 us; speedup 1.0000x reference)
//
#include <hip/hip_runtime.h>
#include <math.h>

#define B_ 8
#define S_ 2048
#define D_ 512
#define HSZ (B_ * S_ * D_)   // 8,388,608 elements

typedef _Float16 half8 __attribute__((ext_vector_type(8)));
typedef _Float16 half4h __attribute__((ext_vector_type(4)));
typedef __fp16 fp16x2 __attribute__((ext_vector_type(2)));
typedef float f32x4 __attribute__((ext_vector_type(4)));
typedef float f32x16 __attribute__((ext_vector_type(16)));
typedef unsigned int u32;

constexpr float INV_SCALE = 0.044194173824159216f; // 1/sqrt(512)

// async global->LDS DMA, 16 B per lane, lane i lands at ldsbase + i*16
__device__ __forceinline__ void gld_lds16(const _Float16* g, _Float16* l) {
    __builtin_amdgcn_global_load_lds(
        (const __attribute__((address_space(1))) unsigned int*)g,
        (__attribute__((address_space(3))) unsigned int*)l, 16, 0, 0);
}

__device__ __forceinline__ u32 pk16(float a, float b) {
    fp16x2 r = __builtin_amdgcn_cvt_pkrtz(a, b);
    union { fp16x2 h; u32 u; } U; U.h = r; return U.u;
}

// ================= cvt_all: fp16 convert + tiled transposes =================
__global__ __launch_bounds__(256) void cvt_all(const float* __restrict__ x,
                                               const float* __restrict__ W,
                                               _Float16* __restrict__ xh,
                                               _Float16* __restrict__ xhT,
                                               _Float16* __restrict__ WhT) {
    __shared__ float T[64 * 65];
    const int tid = threadIdx.x;
    const int blk = blockIdx.x;

    const float* src;
    _Float16* dstT;
    _Float16* dstL;
    int t0, d0, dstTld;
    if (blk < 2048) {
        int b = blk >> 8;
        int r = blk & 255;
        t0 = (r >> 3) * 64; d0 = (r & 7) * 64;
        src = x + (size_t)b * (S_ * D_);
        dstT = xhT + (size_t)b * (S_ * D_); dstTld = S_;
        dstL = xh + (size_t)b * (S_ * D_);
    } else {
        int r = blk - 2048;
        t0 = (r >> 3) * 64; d0 = (r & 7) * 64;
        src = W; dstT = WhT; dstTld = 512; dstL = nullptr;
    }

#pragma unroll
    for (int it = 0; it < 4; ++it) {
        int flat = it * 256 + tid;
        int row = flat >> 4, c4 = (flat & 15) * 4;
        float4 v = *(const float4*)(src + (size_t)(t0 + row) * 512 + d0 + c4);
        T[row * 65 + c4 + 0] = v.x; T[row * 65 + c4 + 1] = v.y;
        T[row * 65 + c4 + 2] = v.z; T[row * 65 + c4 + 3] = v.w;
        if (dstL) {
            half4h h = { (_Float16)v.x, (_Float16)v.y, (_Float16)v.z, (_Float16)v.w };
            *(half4h*)(dstL + (size_t)(t0 + row) * 512 + d0 + c4) = h;
        }
    }
    __syncthreads();
#pragma unroll
    for (int it = 0; it < 2; ++it) {
        int flat = it * 256 + tid;
        int d = flat >> 3, c = (flat & 7) * 8;
        half8 hv;
#pragma unroll
        for (int j = 0; j < 8; ++j) hv[j] = (_Float16)T[(c + j) * 65 + d];
        *(half8*)(dstT + (size_t)(d0 + d) * dstTld + t0 + c) = hv;
    }
}

// ================= MFMA GEMM: qwh = fp16( (xh @ W) * inv_scale ) =============
__global__ __launch_bounds__(256, 2) void gemm_h(const _Float16* __restrict__ xh,
                                                 const _Float16* __restrict__ WhT,
                                                 _Float16* __restrict__ qwh) {
    const int tid = threadIdx.x;
    const int w = tid >> 6, lane = tid & 63, quad = lane >> 4, l16 = lane & 15;
    const int n0 = (blockIdx.x & 3) * 128 + w * 32;
    const int m0 = (blockIdx.x >> 2) * 128;

    half8 Bf[16][2];
#pragma unroll
    for (int kc = 0; kc < 16; ++kc)
#pragma unroll
        for (int nt = 0; nt < 2; ++nt)
            Bf[kc][nt] = *(const half8*)(WhT + (size_t)(n0 + nt * 16 + l16) * 512 + kc * 32 + quad * 8);

    f32x4 acc[8][2];
#pragma unroll
    for (int mt = 0; mt < 8; ++mt)
#pragma unroll
        for (int nt = 0; nt < 2; ++nt) acc[mt][nt] = (f32x4){0.f, 0.f, 0.f, 0.f};

#pragma unroll
    for (int mt = 0; mt < 8; ++mt) {
        const _Float16* arow = xh + (size_t)(m0 + mt * 16 + l16) * 512 + quad * 8;
#pragma unroll
        for (int h = 0; h < 2; ++h) {
            half8 Af[8];
#pragma unroll
            for (int k8 = 0; k8 < 8; ++k8)
                Af[k8] = *(const half8*)(arow + (h * 8 + k8) * 32);
#pragma unroll
            for (int k8 = 0; k8 < 8; ++k8) {
                acc[mt][0] = __builtin_amdgcn_mfma_f32_16x16x32_f16(Af[k8], Bf[h * 8 + k8][0], acc[mt][0], 0, 0, 0);
                acc[mt][1] = __builtin_amdgcn_mfma_f32_16x16x32_f16(Af[k8], Bf[h * 8 + k8][1], acc[mt][1], 0, 0, 0);
            }
        }
    }
#pragma unroll
    for (int mt = 0; mt < 8; ++mt)
#pragma unroll
        for (int nt = 0; nt < 2; ++nt)
#pragma unroll
            for (int r = 0; r < 4; ++r)
                qwh[(size_t)(m0 + mt * 16 + quad * 4 + r) * 512 + n0 + nt * 16 + l16] =
                    (_Float16)(acc[mt][nt][r] * INV_SCALE);
}

// ================= flash6: 32x32 MFMA, in-register softmax ==================
// 4 waves, TQ=32, TK=32, 512 blocks (b = bx&7 one batch per XCD).
// Wave w: k-half h=w&1 of QK (Q resident, 64 VGPR), d-range w*128 of PV.
// S^T = mfma(K, Q): lane holds S[t(r,hi)][q=lane&31]; partner pair (w^1)
// exchanges f32 partial S via 16KB LDS (r=2 QK FLOPs, r=1 LDS streams).
// Softmax fully lane-local; P rebuilt as PV B-frags via cvt_pkrtz + shfl_xor32.
// PV computes O^T = V^T x P^T (V^T A-frags from xhT, L2-resident).
// K tile: global_load_lds, XOR-swizzled 16B chunks (pre-swizzled global src,
// linear LDS dest), conflict-min ds_read_b128 with NO row padding.
// Barrier A: S-exchange visible (V-frags drain, hidden under QK MFMAs).
// Barrier B: next-tile K DMA drains (hidden under softmax+PV).
__global__ __launch_bounds__(256, 2)
void flash6(const _Float16* __restrict__ xh, const _Float16* __restrict__ xhT,
            const _Float16* __restrict__ qwh, float* __restrict__ out) {
    // 65536 B K double-buffer + 16384 B S-exchange = 81920 B (2 blocks/CU)
    __shared__ __align__(16) unsigned char SMEM[81920];
    _Float16* Kb = (_Float16*)SMEM;            // [2][32 rows][512 halves]
    float* Sx = (float*)(SMEM + 65536);        // [4 waves][4 r2][64 lanes][4]

    const int tid = threadIdx.x;
    const int w = tid >> 6, lane = tid & 63;
    const int r31 = lane & 31, hi = lane >> 5;
    const int h = w & 1;                       // k-half for QK
    const int d0w = w * 128;                   // d-range for PV
    const int bx = blockIdx.x;
    const int b = bx & 7;
    const int q0 = (bx >> 3) * 32;
    const size_t xb = (size_t)b * (S_ * D_);

    // Q B-frags (col=q=lane&31, k = h*256 + kc*16 + hi*8), resident.
    half8 Qr[16];
#pragma unroll
    for (int kc = 0; kc < 16; ++kc)
        Qr[kc] = *(const half8*)(qwh + xb + (size_t)(q0 + r31) * 512 + h * 256 + kc * 16 + hi * 8);

    // Prologue: DMA K tile 0, source-swizzled: lane fetches chunk (lane ^ (row&7))
    {
#pragma unroll
        for (int r = 0; r < 8; ++r) {
            int row = w * 8 + r;
            gld_lds16(xh + xb + (size_t)row * 512 + ((lane ^ (row & 7)) << 3),
                      Kb + row * 512);
        }
    }
    __syncthreads();

    f32x16 O[4];
#pragma unroll
    for (int dc = 0; dc < 4; ++dc)
#pragma unroll
        for (int r = 0; r < 16; ++r) O[dc][r] = 0.f;
    float m = -1e30f, l = 0.f;

    const int cb = (h << 5) | hi;   // base 16B-chunk index within K row
    const int s3 = r31 & 7;         // read-side swizzle (matches DMA source swz)

    const int ntiles = S_ / 32;     // 64
    for (int ti = 0; ti < ntiles; ++ti) {
        const int t0 = ti * 32;
        const int cur = ti & 1, nxt = cur ^ 1;

        // ---- issue V^T A-frags early (L2; drains at barrier A under QK) ----
        half8 Vf[8];
#pragma unroll
        for (int dc = 0; dc < 4; ++dc)
#pragma unroll
            for (int kh = 0; kh < 2; ++kh)
                Vf[dc * 2 + kh] = *(const half8*)(xhT + xb +
                    (size_t)(d0w + dc * 32 + r31) * S_ + t0 + kh * 16 + hi * 8);

        // ---- QK partial (k-half h): 16 MFMA, 2 independent chains ----
        f32x16 sa; f32x16 sb;
#pragma unroll
        for (int r = 0; r < 16; ++r) { sa[r] = 0.f; sb[r] = 0.f; }
        const _Float16* kbase = Kb + cur * (32 * 512) + r31 * 512;
#pragma unroll
        for (int kc = 0; kc < 16; kc += 2) {
            half8 A0 = *(const half8*)(kbase + (((cb + 2 * kc) ^ s3) << 3));
            half8 A1 = *(const half8*)(kbase + (((cb + 2 * kc + 2) ^ s3) << 3));
            sa = __builtin_amdgcn_mfma_f32_32x32x16_f16(A0, Qr[kc], sa, 0, 0, 0);
            sb = __builtin_amdgcn_mfma_f32_32x32x16_f16(A1, Qr[kc + 1], sb, 0, 0, 0);
        }
        f32x16 sS = sa + sb;

        // ---- write partial S to LDS (layout [r2][lane]: conflict-min) ----
        {
            float* sxw = Sx + w * 1024;
#pragma unroll
            for (int r2 = 0; r2 < 4; ++r2) {
                f32x4 v = { sS[4 * r2 + 0], sS[4 * r2 + 1], sS[4 * r2 + 2], sS[4 * r2 + 3] };
                *(f32x4*)&sxw[(r2 * 64 + lane) * 4] = v;
            }
        }
        __syncthreads();   // barrier A: S partials visible (V-frags drained)

        // ---- issue DMA for next K tile (drains at barrier B, under PV) ----
        {
            const int t1 = ((ti + 1) & (ntiles - 1)) * 32;   // wrap: harmless
#pragma unroll
            for (int r = 0; r < 8; ++r) {
                int row = w * 8 + r;
                gld_lds16(xh + xb + (size_t)(t1 + row) * 512 + ((lane ^ (row & 7)) << 3),
                          Kb + nxt * (32 * 512) + row * 512);
            }
        }

        // ---- sum partner partial: full S rows for q = lane&31 ----
        float sv[16];
        {
            const float* sxp = Sx + (w ^ 1) * 1024;
#pragma unroll
            for (int r2 = 0; r2 < 4; ++r2) {
                f32x4 pp = *(const f32x4*)&sxp[(r2 * 64 + lane) * 4];
#pragma unroll
                for (int j = 0; j < 4; ++j) sv[4 * r2 + j] = sS[4 * r2 + j] + pp[j];
            }
        }

        // ---- lane-local online softmax (defer-max, THR=8) ----
        float mt = sv[0];
#pragma unroll
        for (int i = 1; i < 16; ++i) mt = fmaxf(mt, sv[i]);
        mt = fmaxf(mt, __shfl_xor(mt, 32));
        if (__any(mt > m + 8.f)) {
            float mn = fmaxf(m, mt);
            float a = __expf(m - mn);
            l *= a;
#pragma unroll
            for (int dc = 0; dc < 4; ++dc)
#pragma unroll
                for (int r = 0; r < 16; ++r) O[dc][r] *= a;
            m = mn;
        }
        float p[16]; float rs = 0.f;
#pragma unroll
        for (int i = 0; i < 16; ++i) { p[i] = __expf(sv[i] - m); rs += p[i]; }
        l += rs + __shfl_xor(rs, 32);

        // ---- build PV B-frags: P[q][t=16kh+8hi+j] via cvt_pk + shfl_xor32 ----
        u32 q16[8];
#pragma unroll
        for (int r2 = 0; r2 < 4; ++r2) {
            q16[2 * r2 + 0] = pk16(p[4 * r2 + 0], p[4 * r2 + 1]);
            q16[2 * r2 + 1] = pk16(p[4 * r2 + 2], p[4 * r2 + 3]);
        }
        half8 Pf[2];
#pragma unroll
        for (int kh = 0; kh < 2; ++kh) {
            int r2o = 2 * kh + hi, r2s = 2 * kh + (hi ^ 1);
            u32 rv0 = (u32)__shfl_xor((int)q16[2 * r2s + 0], 32);
            u32 rv1 = (u32)__shfl_xor((int)q16[2 * r2s + 1], 32);
            u32 o0 = q16[2 * r2o + 0], o1 = q16[2 * r2o + 1];
            union { u32 u[4]; half8 v; } U;
            U.u[0] = hi ? rv0 : o0; U.u[1] = hi ? rv1 : o1;
            U.u[2] = hi ? o0 : rv0; U.u[3] = hi ? o1 : rv1;
            Pf[kh] = U.v;
        }

        // ---- PV: O^T[d,q] += V^T x P^T (4 independent acc chains) ----
#pragma unroll
        for (int dc = 0; dc < 4; ++dc) {
            O[dc] = __builtin_amdgcn_mfma_f32_32x32x16_f16(Vf[dc * 2 + 0], Pf[0], O[dc], 0, 0, 0);
            O[dc] = __builtin_amdgcn_mfma_f32_32x32x16_f16(Vf[dc * 2 + 1], Pf[1], O[dc], 0, 0, 0);
        }
        __syncthreads();   // barrier B: next K tile staged + visible
    }

    // ---- epilogue: O^T/l -> LDS transpose (reuse SMEM) -> coalesced store ----
    {
        float inv = 1.0f / l;
        float* ew = (float*)SMEM + w * 4224;   // 32 rows x 132 (pad) per wave
#pragma unroll
        for (int dc = 0; dc < 4; ++dc)
#pragma unroll
            for (int r = 0; r < 16; ++r) {
                int dl = dc * 32 + (r & 3) + ((r >> 2) << 3) + (hi << 2);
                ew[r31 * 132 + dl] = O[dc][r] * inv;
            }
        // same-wave LDS read-back (compiler inserts lgkmcnt wait)
#pragma unroll
        for (int j = 0; j < 4; ++j) {
            int flat = j * 64 + lane;
            int qq = flat >> 3, c16 = (flat & 7) << 4;
            float* gp = out + xb + (size_t)(q0 + qq) * 512 + d0w + c16;
#pragma unroll
            for (int k = 0; k < 4; ++k)
                *(f32x4*)(gp + k * 4) = *(const f32x4*)&ew[qq * 132 + c16 + k * 4];
        }
    }
}

// ================= fp32 fallback (round 1) ==================================
__global__ __launch_bounds__(256) void xw_gemm_f32(const float* __restrict__ A,
                                                   const float* __restrict__ W,
                                                   float* __restrict__ C) {
    __shared__ float As[16][65];
    __shared__ float Bs[16][64];
    const int tid = threadIdx.x;
    const int row0 = blockIdx.y * 64, col0 = blockIdx.x * 64;
    const int ty = tid / 16, tx = tid % 16;
    float acc[4][4] = {};
    const int ar = tid / 4, ak = (tid % 4) * 4, bk = tid / 16, bn = (tid % 16) * 4;
    for (int k0 = 0; k0 < 512; k0 += 16) {
        float4 a4 = *(const float4*)(A + (size_t)(row0 + ar) * 512 + k0 + ak);
        float4 b4 = *(const float4*)(W + (size_t)(k0 + bk) * 512 + col0 + bn);
        __syncthreads();
        As[ak + 0][ar] = a4.x; As[ak + 1][ar] = a4.y;
        As[ak + 2][ar] = a4.z; As[ak + 3][ar] = a4.w;
        *(float4*)&Bs[bk][bn] = b4;
        __syncthreads();
#pragma unroll
        for (int kk = 0; kk < 16; kk++) {
            float a[4], bv[4];
#pragma unroll
            for (int i = 0; i < 4; i++) a[i] = As[kk][ty * 4 + i];
#pragma unroll
            for (int j = 0; j < 4; j++) bv[j] = Bs[kk][tx * 4 + j];
#pragma unroll
            for (int i = 0; i < 4; i++)
#pragma unroll
                for (int j = 0; j < 4; j++) acc[i][j] += a[i] * bv[j];
        }
    }
#pragma unroll
    for (int i = 0; i < 4; i++) {
        float4 o = make_float4(acc[i][0] * INV_SCALE, acc[i][1] * INV_SCALE,
                               acc[i][2] * INV_SCALE, acc[i][3] * INV_SCALE);
        *(float4*)(C + (size_t)(row0 + ty * 4 + i) * 512 + col0 + tx * 4) = o;
    }
}

__global__ __launch_bounds__(256) void flash_f32(const float* __restrict__ x,
                                                 const float* __restrict__ qw,
                                                 float* __restrict__ out) {
    __shared__ float4 kt[16 * 136];
    const int tid = threadIdx.x;
    const int q = tid >> 3, g = tid & 7;
    const int blk = blockIdx.x;
    const int b = blk >> 6;
    const int qrow = (blk & 63) * 32 + q;
    const size_t xbase = (size_t)b * S_ * D_;
    float qwr[64];
    {
        const float4* p = (const float4*)(qw + xbase + (size_t)qrow * D_ + g * 64);
#pragma unroll
        for (int i4 = 0; i4 < 16; i4++) {
            float4 v = p[i4];
            qwr[4 * i4 + 0] = v.x; qwr[4 * i4 + 1] = v.y;
            qwr[4 * i4 + 2] = v.z; qwr[4 * i4 + 3] = v.w;
        }
    }
    float oa[64];
#pragma unroll
    for (int i = 0; i < 64; i++) oa[i] = 0.f;
    float m = -1e30f, l = 0.f;
    const float4* x4 = (const float4*)(x + xbase);
    for (int t0 = 0; t0 < S_; t0 += 16) {
        __syncthreads();
#pragma unroll
        for (int j = 0; j < 8; j++) {
            int f = tid + j * 256;
            int tt = f >> 7, c = f & 127;
            kt[tt * 136 + (c >> 4) * 17 + (c & 15)] = x4[(size_t)(t0 + tt) * 128 + c];
        }
        __syncthreads();
#pragma unroll 1
        for (int tt = 0; tt < 16; tt++) {
            float4 kv[16];
            const float4* kp = &kt[tt * 136 + g * 17];
#pragma unroll
            for (int i4 = 0; i4 < 16; i4++) kv[i4] = kp[i4];
            float s = 0.f;
#pragma unroll
            for (int i4 = 0; i4 < 16; i4++)
                s += qwr[4 * i4] * kv[i4].x + qwr[4 * i4 + 1] * kv[i4].y
                   + qwr[4 * i4 + 2] * kv[i4].z + qwr[4 * i4 + 3] * kv[i4].w;
            s += __shfl_xor(s, 1, 64); s += __shfl_xor(s, 2, 64); s += __shfl_xor(s, 4, 64);
            if (s > m) {
                float alpha = __expf(m - s);
                l *= alpha;
#pragma unroll
                for (int i = 0; i < 64; i++) oa[i] *= alpha;
                m = s;
            }
            float p = __expf(s - m);
            l += p;
#pragma unroll
            for (int i4 = 0; i4 < 16; i4++) {
                oa[4 * i4 + 0] += p * kv[i4].x; oa[4 * i4 + 1] += p * kv[i4].y;
                oa[4 * i4 + 2] += p * kv[i4].z; oa[4 * i4 + 3] += p * kv[i4].w;
            }
        }
    }
    float inv_l = 1.0f / l;
    float4* op = (float4*)(out + xbase + (size_t)qrow * D_ + g * 64);
#pragma unroll
    for (int i4 = 0; i4 < 16; i4++)
        op[i4] = make_float4(oa[4 * i4] * inv_l, oa[4 * i4 + 1] * inv_l,
                             oa[4 * i4 + 2] * inv_l, oa[4 * i4 + 3] * inv_l);
}

// ================= launch ====================================================
extern "C" void kernel_launch(void* const* d_in, const int* in_sizes, int n_in,
                              void* d_out, int out_size, void* d_ws, size_t ws_size,
                              hipStream_t stream) {
    const float* x = (const float*)d_in[0];
    const float* W = (const float*)d_in[1];
    float* out = (float*)d_out;

    const size_t F16 = (size_t)HSZ * sizeof(_Float16);     // 16,777,216
    const size_t off_qwh = 0;
    const size_t off_xh  = F16;
    const size_t off_xhT = 2 * F16;
    const size_t off_WhT = 3 * F16;
    const size_t base    = 3 * F16 + 512 * 512 * sizeof(_Float16);   // 50,855,936

    if (ws_size >= base) {
        _Float16* qwh = (_Float16*)((char*)d_ws + off_qwh);
        _Float16* xh  = (_Float16*)((char*)d_ws + off_xh);
        _Float16* xhT = (_Float16*)((char*)d_ws + off_xhT);
        _Float16* WhT = (_Float16*)((char*)d_ws + off_WhT);

        cvt_all<<<2112, 256, 0, stream>>>(x, W, xh, xhT, WhT);
        gemm_h<<<512, 256, 0, stream>>>(xh, WhT, qwh);
        flash6<<<512, 256, 0, stream>>>(xh, xhT, qwh, out);
    } else {
        const size_t needf = (size_t)HSZ * sizeof(float);
        float* xw = (ws_size >= needf) ? (float*)d_ws : out;
        dim3 g1(512 / 64, (B_ * S_) / 64);
        xw_gemm_f32<<<g1, 256, 0, stream>>>(x, W, xw);
        flash_f32<<<B_ * (S_ / 32), 256, 0, stream>>>(x, xw, out);
    }
}